// Round 8
// baseline (555.350 us; speedup 1.0000x reference)
//
#include <hip/hip_runtime.h>
#include <hip/hip_bf16.h>

typedef __hip_bfloat16 bf16;
typedef __bf16 bf16x8 __attribute__((ext_vector_type(8)));
typedef float f32x4 __attribute__((ext_vector_type(4)));

#define B_ 4
#define S_ 4096
#define D_ 1024
#define BS_ 16384   // B*S
#define N3_ 3072    // 3*D

__device__ __forceinline__ void gld_lds16(const void* g, void* l) {
    __builtin_amdgcn_global_load_lds(
        (const __attribute__((address_space(1))) void*)g,
        (__attribute__((address_space(3))) void*)l, 16, 0, 0);
}

__device__ __forceinline__ void cast4_one(const float* __restrict__ in,
                                          bf16* __restrict__ out, int i) {
    float4 v = ((const float4*)in)[i];
    union { ushort4 u; bf16 h[4]; } cv;
    cv.h[0] = __float2bfloat16(v.x);
    cv.h[1] = __float2bfloat16(v.y);
    cv.h[2] = __float2bfloat16(v.z);
    cv.h[3] = __float2bfloat16(v.w);
    ((ushort4*)out)[i] = cv.u;
}

// ---- fused prologue: all casts + bias concat + rowsum zero in ONE dispatch ----
__global__ __launch_bounds__(256) void prologue(
    const float* __restrict__ x, const float* __restrict__ wq,
    const float* __restrict__ wk, const float* __restrict__ wv,
    const float* __restrict__ wo, const float* __restrict__ bq,
    const float* __restrict__ bk, const float* __restrict__ bv,
    bf16* __restrict__ xb, bf16* __restrict__ Wc, bf16* __restrict__ Wo,
    float* __restrict__ bc, float* __restrict__ ls) {
    const int blk = blockIdx.x, tid = threadIdx.x;
    if (blk < 16384) {                      // x: 16384*1024/4 float4 chunks
        cast4_one(x, xb, blk * 256 + tid);
    } else if (blk < 20480) {               // 4 weights, 1024 blocks each
        int w = (blk - 16384) >> 10;
        int i = ((blk - 16384) & 1023) * 256 + tid;
        const float* src = (w == 0) ? wq : (w == 1) ? wk : (w == 2) ? wv : wo;
        bf16* dst = (w == 3) ? Wo : Wc + (long)w * D_ * D_;
        cast4_one(src, dst, i);
    } else if (blk < 20544) {               // zero rowsums (16384 floats)
        ls[(blk - 20480) * 256 + tid] = 0.f;
    } else {                                // bias concat (3072)
        for (int i = tid; i < N3_; i += 256)
            bc[i] = (i < 1024) ? bq[i] : (i < 2048) ? bk[i - 1024] : bv[i - 2048];
    }
}

// ---------------- NT GEMM: C(M x 128-col tiles) = A(MxK) * B(NxK)^T, BM x 128 tile, BK=64 ----
// Proven r0 structure (m97-ceiling ~916 TF; within-structure levers measured-null r1-r4).
// LDS rows are 128B (full bank wrap): XOR chunk-col with (row&7); 2 lanes/bank = free [m136].
// EPI 0: +bias, bf16 | 1: exp*scale, bf16 + atomic rowsum | 2: /rowsum, bf16 | 3: +bias, fp32
// EPI 5 (r7/r8): fused QKV projection. y-blocks cover all 3072 weight rows of Wc;
//   n0 <  2048 -> Q/K columns, normal bf16 +bias write into QKV.
//   n0 >= 2048 -> V columns, transposed into VT[b][d][s]. r8: the 128x128 C tile is
//   routed through LDS (aliases As+Bs, exactly 32 KB, dead after the K-loop's final
//   barrier) with a 16B-unit XOR swizzle (u' = u ^ (d&15)); the global store is then
//   16B/lane with 16 consecutive lanes per 256B d-row run — fully coalesced (r7's
//   direct ushort4 scatter made only 32B segments). b = m0>>12 (blocks never span
//   batches: m0 128-aligned, batches 4096-aligned).
template <int EPI, int BM>
__global__ __launch_bounds__(256, 2) void gemm_nt(
    const bf16* __restrict__ A, int lda, long sA,
    const bf16* __restrict__ B, int ldb, long sB,
    void* __restrict__ Cout, int ldc, long sC,
    int K, const float* __restrict__ bias,
    float* __restrict__ rowsum, int sL, float scale,
    bf16* __restrict__ vt) {
    constexpr int MI = BM / 32;                 // 16-row fragment blocks per wave (rows)
    __shared__ __align__(16) bf16 smem[BM * 64 + 128 * 64];  // As | Bs (32 KB @ BM=128)
    bf16* As = smem;
    bf16* Bs = smem + BM * 64;
    const int tid = threadIdx.x;
    const int lane = tid & 63;
    const int wave = tid >> 6;
    const int bz = blockIdx.z;
    const int m0 = blockIdx.x * BM, n0 = blockIdx.y * 128;
    A += (long)bz * sA;
    B += (long)bz * sB;
    rowsum += (long)bz * sL;

    const int wr = (wave >> 1) * (BM / 2);
    const int wc = (wave & 1) * 64;
    const int fm = lane & 15;
    const int q4 = lane >> 4;
    const int sw = fm & 7;                       // row&7 for all fragment rows
    const int rd0 = ((q4 ^ sw) << 3);            // k-half 0 chunk offset (elements)
    const int rd1 = (((4 + q4) ^ sw) << 3);      // k-half 1 chunk offset

    f32x4 zero = {0.f, 0.f, 0.f, 0.f};
    f32x4 acc[MI][4];
#pragma unroll
    for (int i = 0; i < MI; i++)
#pragma unroll
        for (int j = 0; j < 4; j++) acc[i][j] = zero;

    for (int k0 = 0; k0 < K; k0 += 64) {
        // stage A: BM*8 16B-chunks; LDS slot c is fixed, global chunk-col is XOR-swizzled
#pragma unroll
        for (int t = 0; t < BM / 32; t++) {
            int c = tid + t * 256;
            int row = c >> 3;
            int q = (((c & 7) ^ (row & 7)) << 3);
            gld_lds16(A + (long)(m0 + row) * lda + k0 + q, As + c * 8);
        }
#pragma unroll
        for (int t = 0; t < 4; t++) {
            int c = tid + t * 256;
            int row = c >> 3;
            int q = (((c & 7) ^ (row & 7)) << 3);
            gld_lds16(B + (long)(n0 + row) * ldb + k0 + q, Bs + c * 8);
        }
        __syncthreads();
#pragma unroll
        for (int kh = 0; kh < 2; kh++) {
            const int rdo = kh ? rd1 : rd0;
            bf16x8 af[MI], bfr[4];
#pragma unroll
            for (int i = 0; i < MI; i++)
                af[i] = *(const bf16x8*)(As + (wr + i * 16 + fm) * 64 + rdo);
#pragma unroll
            for (int j = 0; j < 4; j++)
                bfr[j] = *(const bf16x8*)(Bs + (wc + j * 16 + fm) * 64 + rdo);
#pragma unroll
            for (int i = 0; i < MI; i++)
#pragma unroll
                for (int j = 0; j < 4; j++)
                    acc[i][j] = __builtin_amdgcn_mfma_f32_16x16x32_bf16(
                        af[i], bfr[j], acc[i][j], 0, 0, 0);
        }
        __syncthreads();
    }

    // C/D layout: col = lane&15, row = (lane>>4)*4 + reg  [m89/m91]
    if constexpr (EPI == 5) {
        if (n0 >= 2048) {
            // ---- V block: transpose via LDS (T aliases As+Bs = 128x128 bf16) ----
            bf16* T = smem;                      // row = d_local, col = s_local
            const int b = m0 >> 12;
            const int sbase = m0 & 4095;
            // write: ushort4 (4 consecutive s) at 16B-unit u' = u ^ (d&15); d&15==fm
#pragma unroll
            for (int i = 0; i < MI; i++) {
                const int s0 = wr + i * 16 + q4 * 4;      // local s, 4-aligned
                const int ub = s0 >> 3;                   // 16B unit index
                const int uh = ((s0 >> 2) & 1) << 2;      // 4-elem half offset
#pragma unroll
                for (int j = 0; j < 4; j++) {
                    const int dl = wc + j * 16 + fm;      // local d; dl&15 == fm
                    const float bvv = bias[n0 + dl];
                    union { ushort4 u; bf16 h[4]; } pk;
#pragma unroll
                    for (int r = 0; r < 4; r++)
                        pk.h[r] = __float2bfloat16(acc[i][j][r] + bvv);
                    *(ushort4*)(T + dl * 128 + ((ub ^ fm) << 3) + uh) = pk.u;
                }
            }
            __syncthreads();
            // read de-swizzled + coalesced store: 16 consecutive lanes = one d-row
            const int dl0 = tid >> 4;                     // 0..15
            const int uc  = tid & 15;                     // s unit 0..15
#pragma unroll
            for (int k = 0; k < 8; k++) {
                const int dl = dl0 + k * 16;
                bf16x8 v = *(const bf16x8*)(T + dl * 128 + ((uc ^ (dl & 15)) << 3));
                *(bf16x8*)(vt + (long)b * D_ * S_ +
                           (long)(n0 - 2048 + dl) * S_ + sbase + uc * 8) = v;
            }
            return;
        }
    }
    (void)vt;

#pragma unroll
    for (int i = 0; i < MI; i++)
#pragma unroll
        for (int r = 0; r < 4; r++) {
            const int grow = m0 + wr + q4 * 4 + i * 16 + r;
            if constexpr (EPI == 0 || EPI == 5) {
#pragma unroll
                for (int j = 0; j < 4; j++) {
                    int gcol = n0 + wc + j * 16 + fm;
                    ((bf16*)Cout)[(long)bz * sC + (long)grow * ldc + gcol] =
                        __float2bfloat16(acc[i][j][r] + bias[gcol]);
                }
            } else if constexpr (EPI == 1) {
                float s = 0.f;
#pragma unroll
                for (int j = 0; j < 4; j++) {
                    int gcol = n0 + wc + j * 16 + fm;
                    float v = __expf(acc[i][j][r] * scale);
                    bf16 hv = __float2bfloat16(v);
                    ((bf16*)Cout)[(long)bz * sC + (long)grow * ldc + gcol] = hv;
                    s += __bfloat162float(hv);  // sum what we actually stored
                }
                s += __shfl_xor(s, 1, 16);
                s += __shfl_xor(s, 2, 16);
                s += __shfl_xor(s, 4, 16);
                s += __shfl_xor(s, 8, 16);
                if (fm == 0) atomicAdd(rowsum + grow, s);
            } else if constexpr (EPI == 2) {
                float inv = 1.0f / rowsum[grow];
#pragma unroll
                for (int j = 0; j < 4; j++) {
                    int gcol = n0 + wc + j * 16 + fm;
                    ((bf16*)Cout)[(long)bz * sC + (long)grow * ldc + gcol] =
                        __float2bfloat16(acc[i][j][r] * inv);
                }
            } else {
#pragma unroll
                for (int j = 0; j < 4; j++) {
                    int gcol = n0 + wc + j * 16 + fm;
                    ((float*)Cout)[(long)bz * sC + (long)grow * ldc + gcol] =
                        acc[i][j][r] + bias[gcol];
                }
            }
        }
}

extern "C" void kernel_launch(void* const* d_in, const int* in_sizes, int n_in,
                              void* d_out, int out_size, void* d_ws, size_t ws_size,
                              hipStream_t stream) {
    const float* x  = (const float*)d_in[0];
    const float* wq = (const float*)d_in[1];
    const float* bq = (const float*)d_in[2];
    const float* wk = (const float*)d_in[3];
    const float* bk = (const float*)d_in[4];
    const float* wv = (const float*)d_in[5];
    const float* bv = (const float*)d_in[6];
    const float* wo = (const float*)d_in[7];
    const float* bo = (const float*)d_in[8];
    (void)in_sizes; (void)n_in; (void)out_size;

    // base ws carve: 104.07 MiB (proven to fit)
    char* p = (char*)d_ws;
    bf16* Wc  = (bf16*)p;  p += (long)N3_ * D_ * 2;   // 6 MiB
    bf16* Wo  = (bf16*)p;  p += (long)D_ * D_ * 2;    // 2 MiB
    float* bc = (float*)p; p += N3_ * 4;              // 12 KiB
    bf16* QKV = (bf16*)p;  p += (long)BS_ * N3_ * 2;  // 96 MiB; Q cols become At
    float* ls = (float*)p; p += (long)BS_ * 4;        // 64 KiB
    // base end = 109,129,728 bytes

    bf16* xb = (bf16*)d_out;                          // 32 MiB; dead after QKV GEMM

    const size_t base = 109129728UL;
    int tier;
    bf16 *VT, *E;
    if (ws_size >= base + 134217728UL) {
        tier = 2;
        E  = (bf16*)p;                                // 128 MiB in ws
        VT = (bf16*)((char*)d_out + 33554432);        // 32 MiB upper half of d_out
    } else if (ws_size >= base + 33554432UL) {
        tier = 1;
        VT = (bf16*)p;                                // 32 MiB in ws
        E  = (bf16*)d_out;                            // 2 slots x 32 MiB
    } else {
        tier = 0;
        VT = (bf16*)((char*)d_out + 33554432);
        E  = (bf16*)d_out;                            // 1 slot
    }
    // VT is disjoint from xb (lower 32 MiB of d_out) in every tier, so the
    // fused projection GEMM may write VT while reading xb.

    // 1) fused prologue
    prologue<<<dim3(20545), 256, 0, stream>>>(x, wq, wk, wv, wo, bq, bk, bv,
                                              xb, Wc, Wo, bc, ls);

    // 2) fused projections: Q,K -> QKV cols [0,2048); V -> VT transposed
    //    (M=16384, N=3072, K=1024 in ONE dispatch; y>=16 blocks are V)
    gemm_nt<5, 128><<<dim3(BS_ / 128, N3_ / 128, 1), 256, 0, stream>>>(
        xb, D_, 0, Wc, D_, 0, QKV, N3_, 0, D_, bc, ls, 0, 1.f, VT);

    // 3) attention: E = exp(QK^T/32) (+rowsum), At = (E V)/rowsum -> Q region
    if (tier == 2) {
        gemm_nt<1, 128><<<dim3(32, 32, 4), 256, 0, stream>>>(
            QKV, N3_, (long)S_ * N3_, QKV + 1024, N3_, (long)S_ * N3_,
            E, S_, (long)S_ * S_, D_, nullptr, ls, S_, 0.03125f, nullptr);
        gemm_nt<2, 128><<<dim3(32, 8, 4), 256, 0, stream>>>(
            E, S_, (long)S_ * S_, VT, S_, (long)D_ * S_,
            QKV, N3_, (long)S_ * N3_, S_, nullptr, ls, S_, 1.f, nullptr);
    } else if (tier == 1) {
        for (int pr = 0; pr < 2; ++pr) {
            const long qoff = (long)(2 * pr) * S_ * N3_;
            gemm_nt<1, 128><<<dim3(32, 32, 2), 256, 0, stream>>>(
                QKV + qoff, N3_, (long)S_ * N3_,
                QKV + qoff + 1024, N3_, (long)S_ * N3_,
                E, S_, (long)S_ * S_, D_, nullptr, ls + 2 * pr * S_, S_, 0.03125f, nullptr);
            gemm_nt<2, 128><<<dim3(32, 8, 2), 256, 0, stream>>>(
                E, S_, (long)S_ * S_,
                VT + (long)(2 * pr) * D_ * S_, S_, (long)D_ * S_,
                QKV + qoff, N3_, (long)S_ * N3_, S_, nullptr, ls + 2 * pr * S_, S_, 1.f, nullptr);
        }
    } else {
        for (int b = 0; b < B_; ++b) {
            const long qoff = (long)b * S_ * N3_;
            gemm_nt<1, 128><<<dim3(32, 32, 1), 256, 0, stream>>>(
                QKV + qoff, N3_, 0, QKV + qoff + 1024, N3_, 0,
                E, S_, 0, D_, nullptr, ls + b * S_, 0, 0.03125f, nullptr);
            gemm_nt<2, 64><<<dim3(64, 8, 1), 256, 0, stream>>>(
                E, S_, 0, VT + (long)b * D_ * S_, S_, 0,
                QKV + qoff, N3_, 0, S_, nullptr, ls + b * S_, 0, 1.f, nullptr);
        }
    }

    // 5) out = At @ Wo^T + bo -> fp32  (M=16384, N=1024, K=1024; A row stride 3072)
    gemm_nt<3, 128><<<dim3(BS_ / 128, D_ / 128, 1), 256, 0, stream>>>(
        QKV, N3_, 0, Wo, D_, 0, d_out, D_, 0, D_, bo, ls, 0, 1.f, nullptr);
}